// Round 10
// baseline (113.761 us; speedup 1.0000x reference)
//
#include <hip/hip_runtime.h>

// LIF scan: z [B=32, T=1024, H=512] fp32 -> out [32,1024,512] fp32
//   V_t = 0.9*V_{t-1} + z[:,t-1,:] - (V_{t-1} > 1)      (exact fp32 op order)
//   out[:,t,:] = (V_t > 1) ? 1 : 0,  out[:,0,:] = 0
//
// Evidence ladder:
//   R4 42.7us | R5 depth: worse | R6 fat blocks: per-CU cap | R7 extra pass:
//   worse | R8 ripple: worse | R9 XCD decode: ~+3% | R10 more prod waves:
//   worse | R11 NT stores: ~+5%. Reads+writes both 256B-island streams;
//   R7 showed the READ side alone costs ~35us -> reads are the binding pole.
// R12 theory: DRAM page locality needs TEMPORAL alignment. The 8 siblings
//   read 256B islands of each 2KB row (~1 HBM page) microseconds apart ->
//   8 activations per page, 256B each. Placement (R9) can't fix timing.
//   Fix: WARMING. Sibling s fire-and-forget prefetches FULL 2KB rows for
//   rows t%8==s of chunk c+2 (GLDS into 1KB scratch, never waited, never
//   read) -> each page fetched ONCE as contiguous 1KB bursts into the
//   shared XCD L2 (R9 decode = prerequisite); island reads one phase later
//   hit L2. Producers drain islands only, via counted vmcnt(8) (vmcnt
//   retires in issue order; warms are the 8 newest).
//   Keeps: R9 decode, R11 NT spike stores.

#define LIF_H 512
#define LIF_T 1024
#define CH 128            // timesteps per superchunk (32 KB per buffer)
#define NCH 8
#define NPROD 4
#define NTHREADS (64 * (1 + NPROD))

#define GLDS(gptr, lptr)                                                     \
    __builtin_amdgcn_global_load_lds(                                        \
        (const __attribute__((address_space(1))) void*)(gptr),               \
        (__attribute__((address_space(3))) void*)(lptr), 16, 0, 0)

__global__ __launch_bounds__(NTHREADS, 1) void lif_kernel(const float* __restrict__ z,
                                                          float* __restrict__ out) {
    __shared__ float lds[2][CH * 64];
    __shared__ float wscr[256];         // 1 KB warm scratch (garbage sink)

    const int tid  = threadIdx.x;
    const int wave = tid >> 6;
    const int lane = tid & 63;
    const int bid  = blockIdx.x;        // 0..255
    // R9 decode: XCD = bid%8 = b%8 -> the 8 h-slice siblings of a batch
    // share one XCD L2 (prerequisite for warming).
    const int b    = bid & 31;          // batch
    const int s    = bid >> 5;          // h-slice 0..7
    const int h0   = s << 6;

    const float* zbat = z + b * (LIF_T * LIF_H);        // full-row base
    const float* zb   = zbat + h0;                      // island base
    float*       ob   = out + b * (LIF_T * LIF_H) + h0;

    // Warm rows t of chunk cc with t%8 == s; producer p takes 4 of the 16.
    // Each row = 2 x GLDS(1KB). Fire-and-forget: no waitcnt, scratch dst.
#define WARM(cc, p)                                                          \
    _Pragma("unroll")                                                        \
    for (int k = 0; k < 4; ++k) {                                            \
        const float* wr = zbat + ((cc) * CH + (p) * 32 + k * 8 + s) * LIF_H; \
        GLDS(wr + lane * 4, wscr);                                           \
        GLDS(wr + 256 + lane * 4, wscr);                                     \
    }

    // ---- prologue: islands chunk 0 + warm chunk 1; zero t=0 row ----
    if (wave == 0) {
        __builtin_nontemporal_store(0.0f, &ob[lane]);
    } else {
        const int p = wave - 1;         // 0..3
#pragma unroll
        for (int j = 0; j < 8; ++j) {
            const int r0 = p * 32 + j * 4;
            GLDS(zb + (r0 + (lane >> 4)) * LIF_H + (lane & 15) * 4,
                 &lds[0][r0 * 64]);
        }
        WARM(1, p);
        __builtin_amdgcn_sched_barrier(0);
        asm volatile("s_waitcnt vmcnt(8)" ::: "memory");  // islands0 done
    }
    __builtin_amdgcn_s_barrier();

    float V = 0.0f;
    float r = 0.0f;                     // reset = previous spike (V0=0 -> 0)

#define LDRB(rb, sub)                                                        \
    _Pragma("unroll")                                                        \
    for (int i = 0; i < 32; ++i) rb[i] = lb[((sub) * 32 + i) * 64 + lane];

#define CHAIN(rb, s0, N)                                                     \
    _Pragma("unroll")                                                        \
    for (int i = 0; i < (N); ++i) {                                          \
        const float u  = __fadd_rn(__fmul_rn(0.9f, V), rb[i]);               \
        const float Vn = __fsub_rn(u, r);                                    \
        const float sp = (Vn > 1.0f) ? 1.0f : 0.0f;                          \
        __builtin_nontemporal_store(sp, &ob[((s0) + i + 1) * LIF_H + lane]); \
        r = sp;                                                              \
        V = Vn;                                                              \
    }

#pragma unroll 1
    for (int c = 0; c < NCH; ++c) {
        if (wave > 0) {
            // ---- producers: islands c+1, warm c+2, drain islands only ----
            if (c + 1 < NCH) {
                const int p = wave - 1;
                float* dst = lds[(c + 1) & 1];
                const float* src = zb + (c + 1) * CH * LIF_H;
#pragma unroll
                for (int j = 0; j < 8; ++j) {
                    const int r0 = p * 32 + j * 4;
                    GLDS(src + (r0 + (lane >> 4)) * LIF_H + (lane & 15) * 4,
                         &dst[r0 * 64]);
                }
                if (c + 2 < NCH) {
                    WARM(c + 2, p);
                    __builtin_amdgcn_sched_barrier(0);
                    asm volatile("s_waitcnt vmcnt(8)" ::: "memory");
                } else {
                    __builtin_amdgcn_sched_barrier(0);
                    asm volatile("s_waitcnt vmcnt(0)" ::: "memory");
                }
            }
        } else {
            // ---- consumer: scan chunk c from LDS (reg double-buffered) ----
            const float* lb = lds[c & 1];
            const int s0 = c * CH;
            float rbA[32], rbB[32];
            LDRB(rbA, 0);
            LDRB(rbB, 1);
            __builtin_amdgcn_sched_barrier(0);
            CHAIN(rbA, s0 + 0, 32);
            LDRB(rbA, 2);
            __builtin_amdgcn_sched_barrier(0);
            CHAIN(rbB, s0 + 32, 32);
            LDRB(rbB, 3);
            __builtin_amdgcn_sched_barrier(0);
            CHAIN(rbA, s0 + 64, 32);
            __builtin_amdgcn_sched_barrier(0);
            if (c < NCH - 1) {
                CHAIN(rbB, s0 + 96, 32);
            } else {
                CHAIN(rbB, s0 + 96, 31);   // steps 992..1022
            }
        }
        __builtin_amdgcn_s_barrier();
    }
}

extern "C" void kernel_launch(void* const* d_in, const int* in_sizes, int n_in,
                              void* d_out, int out_size, void* d_ws, size_t ws_size,
                              hipStream_t stream) {
    const float* z = (const float*)d_in[0];
    float* out = (float*)d_out;
    hipLaunchKernelGGL(lif_kernel, dim3(256), dim3(NTHREADS), 0, stream, z, out);
}